// Round 15
// baseline (72.637 us; speedup 1.0000x reference)
//
#include <hip/hip_runtime.h>
#include <math.h>

// Problem constants (reference: POS_LEN=32, NUM_F=16, HIDDEN=256, T=32)
#define NUM_F   16
#define FIN     (8 * NUM_F)      // 128 fourier features
#define HIDDEN  256
#define TOUT    32
#define NOFF    63               // distinct offset values: -31..31
#define NSUM    125              // distinct dr+dc / dr-dc values: -62..62
#define PROWS   (NOFF + NOFF + NSUM + NSUM)      // 376 rows in P
#define RSTRIDE 36               // rows[] float stride (9 float4, bank-spread)

// ---------------------------------------------------------------------------
// KP: layer-1 separable partials P[rho][h] (proven, ~1.5 us).
//   rho 0..62 Pa(dr) | 63..125 Pb(dc) | 126..250 Pp(dr+dc) | 251..375 Pm(dr-dc)
__global__ __launch_bounds__(256) void gab_ptab_kernel(
    const float* __restrict__ freqs, const float* __restrict__ W1,
    float* __restrict__ P)
{
    __shared__ float fv[32];
    const int rho = blockIdx.x;
    int grp, val;
    if (rho < NOFF)                 { grp = 0; val = rho - 31; }
    else if (rho < 2 * NOFF)        { grp = 1; val = rho - NOFF - 31; }
    else if (rho < 2 * NOFF + NSUM) { grp = 2; val = rho - 2 * NOFF - 62; }
    else                            { grp = 3; val = rho - 2 * NOFF - NSUM - 62; }
    const int t = threadIdx.x;
    if (t < 32) {
        const float arg = (float)val * freqs[t & 15];
        fv[t] = (t < 16) ? sinf(arg) : cosf(arg);   // [sin16, cos16]
    }
    __syncthreads();
    const float4* __restrict__ w4 = (const float4*)(W1 + t * FIN + grp * 32);
    const float4* f4 = (const float4*)fv;           // same-addr broadcast
    float a0 = 0.f, a1 = 0.f, a2 = 0.f, a3 = 0.f;
    #pragma unroll
    for (int k = 0; k < 8; k += 2) {
        const float4 wa = w4[k], wb = w4[k + 1];
        const float4 fa = f4[k], fb = f4[k + 1];
        a0 = fmaf(wa.x, fa.x, a0); a1 = fmaf(wa.y, fa.y, a1);
        a2 = fmaf(wa.z, fa.z, a2); a3 = fmaf(wa.w, fa.w, a3);
        a0 = fmaf(wb.x, fb.x, a0); a1 = fmaf(wb.y, fb.y, a1);
        a2 = fmaf(wb.z, fb.z, a2); a3 = fmaf(wb.w, fb.w, a3);
    }
    P[rho * HIDDEN + t] = (a0 + a1) + (a2 + a3);
}

// ---------------------------------------------------------------------------
// KTILE: one block per 32x32 output tile (bi,bj). dr = bi-bj is FIXED, so the
// tile needs only 63 table rows (dc = -31..31). Wave w computes rows
// dcx = w, w+4, ... (R7 structure: lane l owns h[4l..4l+3]; W2 in 128 VGPRs;
// halving shuffle reduce; lanes<32 write rows[dcx][bitrev5]). One barrier,
// then 32 contiguous 4-KB segment writes (ds_read_b128 + float4 store).
// Cold P/W2 misses and the 16x row redundancy hide under the write stream.
__global__ __launch_bounds__(256, 2) void gab_tile_kernel(
    const float* __restrict__ P, const float* __restrict__ b1,
    const float* __restrict__ W2, const float* __restrict__ b2,
    float4* __restrict__ out)
{
    __shared__ float rows[NOFF][RSTRIDE];     // 63 rows x 32 outs (padded)

    const int t  = threadIdx.x;
    const int l  = t & 63;
    const int w  = t >> 6;                    // wave 0..3
    const int bi = blockIdx.x >> 5;
    const int bj = blockIdx.x & 31;
    const int ia = (bi - bj) + 31;            // dr + 31, fixed for the tile

    // ---- per-lane invariants -------------------------------------------
    const float4* __restrict__ P4 = (const float4*)P;
    const float4 bb = ((const float4*)b1)[l];
    const float4 pa = P4[ia * 64 + l];
    const float bx = pa.x + bb.x, by = pa.y + bb.y,
                bz = pa.z + bb.z, bw = pa.w + bb.w;

    float4 w2r[32];                           // W2[o][4l..4l+3], 128 VGPRs
    const float4* __restrict__ W24 = (const float4*)W2;
    #pragma unroll
    for (int o = 0; o < 32; ++o) w2r[o] = W24[o * 64 + l];

    const float* __restrict__ Pb4 = (const float*)(P + NOFF * HIDDEN);
    const float* __restrict__ Pp4 = (const float*)(P + 2 * NOFF * HIDDEN);
    const float* __restrict__ Pm4 = (const float*)(P + (2 * NOFF + NSUM) * HIDDEN);

    // ---- compute this wave's rows (no barriers inside) -------------------
    for (int dcx = w; dcx < NOFF; dcx += 4) {
        const float4 pb = ((const float4*)Pb4)[dcx * 64 + l];
        const float4 pp = ((const float4*)Pp4)[(ia + dcx) * 64 + l];
        const float4 pm = ((const float4*)Pm4)[(ia - dcx + 62) * 64 + l];

        float h0 = bx + pb.x + pp.x + pm.x;
        float h1 = by + pb.y + pp.y + pm.y;
        float h2 = bz + pb.z + pp.z + pm.z;
        float h3 = bw + pb.w + pp.w + pm.w;
        h0 = h0 / (1.0f + expf(-h0));
        h1 = h1 / (1.0f + expf(-h1));
        h2 = h2 / (1.0f + expf(-h2));
        h3 = h3 / (1.0f + expf(-h3));

        float acc[32];
        #pragma unroll
        for (int o = 0; o < 32; ++o) {
            const float4 ww = w2r[o];
            acc[o] = fmaf(ww.x, h0, fmaf(ww.y, h1, fmaf(ww.z, h2, ww.w * h3)));
        }
        // vector-halving shuffle reduce (static indices, proven R7)
        #pragma unroll
        for (int i = 0; i < 16; ++i) {
            const float keep = (l & 1) ? acc[i + 16] : acc[i];
            const float send = (l & 1) ? acc[i] : acc[i + 16];
            acc[i] = keep + __shfl_xor(send, 1);
        }
        #pragma unroll
        for (int i = 0; i < 8; ++i) {
            const float keep = (l & 2) ? acc[i + 8] : acc[i];
            const float send = (l & 2) ? acc[i] : acc[i + 8];
            acc[i] = keep + __shfl_xor(send, 2);
        }
        #pragma unroll
        for (int i = 0; i < 4; ++i) {
            const float keep = (l & 4) ? acc[i + 4] : acc[i];
            const float send = (l & 4) ? acc[i] : acc[i + 4];
            acc[i] = keep + __shfl_xor(send, 4);
        }
        #pragma unroll
        for (int i = 0; i < 2; ++i) {
            const float keep = (l & 8) ? acc[i + 2] : acc[i];
            const float send = (l & 8) ? acc[i] : acc[i + 2];
            acc[i] = keep + __shfl_xor(send, 8);
        }
        {
            const float keep = (l & 16) ? acc[1] : acc[0];
            const float send = (l & 16) ? acc[0] : acc[1];
            acc[0] = keep + __shfl_xor(send, 16);
        }
        const float tot = acc[0] + __shfl_xor(acc[0], 32);

        if (l < 32) {
            const int o = ((l & 1) << 4) | ((l & 2) << 2) | (l & 4)
                        | ((l & 8) >> 2) | ((l & 16) >> 4);   // bitrev5(l)
            rows[dcx][o] = (tot + b2[o]) * 0.17677669529663687f; // /sqrt(32)
        }
    }
    __syncthreads();                           // rows ready

    // ---- write phase: 32 contiguous 4-KB segments ------------------------
    // thread t covers (jj = t>>3, o4 = t&7); row index r = ii - jj + 31.
    const int jj = t >> 3;
    const int o4 = t & 7;
    const float4* __restrict__ rows4 = (const float4*)rows;  // stride 9 f4
    #pragma unroll 4
    for (int ii = 0; ii < 32; ++ii) {
        const int i = (bi << 5) + ii;
        const long seg = ((long)i << 13) + ((long)bj << 8);  // (i*1024+bj*32)*8
        const float4 v = rows4[(ii - jj + 31) * 9 + o4];
        out[seg + t] = v;
    }
}

// ---------------------------------------------------------------------------
extern "C" void kernel_launch(void* const* d_in, const int* in_sizes, int n_in,
                              void* d_out, int out_size, void* d_ws, size_t ws_size,
                              hipStream_t stream) {
    // inputs: 0 seq_len 1 freqs(16) 2 W1(256*128) 3 b1(256) 4 W2(32*256)
    //         5 b2(32) 6 dr(S*S) 7 dc(S*S)
    const float* freqs = (const float*)d_in[1];
    const float* W1    = (const float*)d_in[2];
    const float* b1    = (const float*)d_in[3];
    const float* W2    = (const float*)d_in[4];
    const float* b2    = (const float*)d_in[5];
    float4* out = (float4*)d_out;

    float* P = (float*)d_ws;                   // 376*256*4 = 385 KB scratch

    gab_ptab_kernel<<<PROWS, 256, 0, stream>>>(freqs, W1, P);
    gab_tile_kernel<<<1024, 256, 0, stream>>>(P, b1, W2, b2, out);
}

// Round 16
// 46.691 us; speedup vs baseline: 1.5557x; 1.5557x over previous
//
#include <hip/hip_runtime.h>
#include <math.h>

// Problem constants (reference: POS_LEN=32, NUM_F=16, HIDDEN=256, T=32)
#define NUM_F   16
#define FIN     (8 * NUM_F)      // 128 fourier features
#define HIDDEN  256
#define TOUT    32
#define NOFF    63               // distinct offset values: -31..31
#define NSUM    125              // distinct dr+dc / dr-dc values: -62..62
#define NPAIRS_TBL (NOFF * NOFF) // 3969
#define PROWS   (NOFF + NOFF + NSUM + NSUM)      // 376 rows in P

// ---------------------------------------------------------------------------
// KP: layer-1 separable partials P[rho][h] (proven ~1.5 us).
// NT store: leave P CLEAN (L3/HBM), not dirty in this XCD's L2 — avoids
// cross-XCD dirty-line writeback serialization when KT reads it.
__global__ __launch_bounds__(256) void gab_ptab_kernel(
    const float* __restrict__ freqs, const float* __restrict__ W1,
    float* __restrict__ P)
{
    __shared__ float fv[32];
    const int rho = blockIdx.x;
    int grp, val;
    if (rho < NOFF)                 { grp = 0; val = rho - 31; }
    else if (rho < 2 * NOFF)        { grp = 1; val = rho - NOFF - 31; }
    else if (rho < 2 * NOFF + NSUM) { grp = 2; val = rho - 2 * NOFF - 62; }
    else                            { grp = 3; val = rho - 2 * NOFF - NSUM - 62; }
    const int t = threadIdx.x;
    if (t < 32) {
        const float arg = (float)val * freqs[t & 15];
        fv[t] = (t < 16) ? sinf(arg) : cosf(arg);   // [sin16, cos16]
    }
    __syncthreads();
    const float4* __restrict__ w4 = (const float4*)(W1 + t * FIN + grp * 32);
    const float4* f4 = (const float4*)fv;           // same-addr broadcast
    float a0 = 0.f, a1 = 0.f, a2 = 0.f, a3 = 0.f;
    #pragma unroll
    for (int k = 0; k < 8; k += 2) {
        const float4 wa = w4[k], wb = w4[k + 1];
        const float4 fa = f4[k], fb = f4[k + 1];
        a0 = fmaf(wa.x, fa.x, a0); a1 = fmaf(wa.y, fa.y, a1);
        a2 = fmaf(wa.z, fa.z, a2); a3 = fmaf(wa.w, fa.w, a3);
        a0 = fmaf(wb.x, fb.x, a0); a1 = fmaf(wb.y, fb.y, a1);
        a2 = fmaf(wb.z, fb.z, a2); a3 = fmaf(wb.w, fb.w, a3);
    }
    __builtin_nontemporal_store((a0 + a1) + (a2 + a3), &P[rho * HIDDEN + t]);
}

// ---------------------------------------------------------------------------
// KT (R14 structure): wave-per-pair, W2 staged in LDS, early P loads.
// NT store for the table: leave it clean for the gather.
__global__ __launch_bounds__(256) void gab_table_kernel(
    const float* __restrict__ P, const float* __restrict__ b1,
    const float* __restrict__ W2, const float* __restrict__ b2,
    float* __restrict__ table)
{
    __shared__ float4 w2s[2048];                  // 32 KB: all of W2 as f4

    const int t    = threadIdx.x;
    const int pair = blockIdx.x * 4 + (t >> 6);
    const int l    = t & 63;
    const bool valid = (pair < NPAIRS_TBL);
    const int cp   = valid ? pair : (NPAIRS_TBL - 1);   // clamp: safe loads

    // ---- issue P/b1 loads early (latency overlaps W2 staging) -----------
    const int ia = cp / NOFF;                    // dr + 31
    const int ib = cp % NOFF;                    // dc + 31
    const int ip = ia + ib;
    const int im = ia - ib + 62;
    const float4* __restrict__ P4 = (const float4*)P;
    const float4 pa = P4[(0 * NOFF          + ia) * 64 + l];
    const float4 pb = P4[(1 * NOFF          + ib) * 64 + l];
    const float4 pp = P4[(2 * NOFF          + ip) * 64 + l];
    const float4 pm = P4[((2 * NOFF + NSUM) + im) * 64 + l];
    const float4 bb = ((const float4*)b1)[l];

    // ---- stage W2 -> LDS (coalesced, 8 f4/thread) -------------------------
    const float4* __restrict__ W24 = (const float4*)W2;
    #pragma unroll
    for (int k = 0; k < 8; ++k) w2s[k * 256 + t] = W24[k * 256 + t];
    __syncthreads();

    // ---- hidden: h[4l..4l+3] ----------------------------------------------
    float h0 = pa.x + pb.x + pp.x + pm.x + bb.x;
    float h1 = pa.y + pb.y + pp.y + pm.y + bb.y;
    float h2 = pa.z + pb.z + pp.z + pm.z + bb.z;
    float h3 = pa.w + pb.w + pp.w + pm.w + bb.w;
    h0 = h0 / (1.0f + expf(-h0));
    h1 = h1 / (1.0f + expf(-h1));
    h2 = h2 / (1.0f + expf(-h2));
    h3 = h3 / (1.0f + expf(-h3));

    // ---- layer 2 from LDS (b128, conflict-free) ---------------------------
    float acc[32];
    #pragma unroll
    for (int o = 0; o < 32; ++o) {
        const float4 w = w2s[o * 64 + l];
        acc[o] = fmaf(w.x, h0, fmaf(w.y, h1, fmaf(w.z, h2, w.w * h3)));
    }

    // ---- vector-halving shuffle reduce (static indices) -------------------
    #pragma unroll
    for (int i = 0; i < 16; ++i) {
        const float keep = (l & 1) ? acc[i + 16] : acc[i];
        const float send = (l & 1) ? acc[i] : acc[i + 16];
        acc[i] = keep + __shfl_xor(send, 1);
    }
    #pragma unroll
    for (int i = 0; i < 8; ++i) {
        const float keep = (l & 2) ? acc[i + 8] : acc[i];
        const float send = (l & 2) ? acc[i] : acc[i + 8];
        acc[i] = keep + __shfl_xor(send, 2);
    }
    #pragma unroll
    for (int i = 0; i < 4; ++i) {
        const float keep = (l & 4) ? acc[i + 4] : acc[i];
        const float send = (l & 4) ? acc[i] : acc[i + 4];
        acc[i] = keep + __shfl_xor(send, 4);
    }
    #pragma unroll
    for (int i = 0; i < 2; ++i) {
        const float keep = (l & 8) ? acc[i + 2] : acc[i];
        const float send = (l & 8) ? acc[i] : acc[i + 2];
        acc[i] = keep + __shfl_xor(send, 8);
    }
    {
        const float keep = (l & 16) ? acc[1] : acc[0];
        const float send = (l & 16) ? acc[0] : acc[1];
        acc[0] = keep + __shfl_xor(send, 16);
    }
    const float tot = acc[0] + __shfl_xor(acc[0], 32);

    if (valid && l < 32) {
        const int o = ((l & 1) << 4) | ((l & 2) << 2) | (l & 4)
                    | ((l & 8) >> 2) | ((l & 16) >> 4);   // bitrev5(l)
        __builtin_nontemporal_store(
            (tot + b2[o]) * 0.17677669529663687f, &table[pair * TOUT + o]);
    }
}

// ---------------------------------------------------------------------------
// Gather (plain stores — measured at the ~20.8 us write floor when the table
// is clean).
__global__ __launch_bounds__(256) void gab_gather_kernel(
    const float* __restrict__ table,
    float4* __restrict__ out, int npairs)
{
    const int total = npairs * 8;
    const int stride = gridDim.x * blockDim.x;
    const float4* __restrict__ tbl4 = (const float4*)table;
    for (int idx = blockIdx.x * blockDim.x + threadIdx.x; idx < total; idx += stride) {
        const int p = idx >> 3;
        const int l = idx & 7;
        const int i = p >> 10;
        const int j = p & 1023;
        const int ir = (i >> 5) - (j >> 5) + (NOFF / 2);
        const int ic = (i & 31) - (j & 31) + (NOFF / 2);
        out[idx] = tbl4[(ir * NOFF + ic) * (TOUT / 4) + l];
    }
}

// ---------------------------------------------------------------------------
extern "C" void kernel_launch(void* const* d_in, const int* in_sizes, int n_in,
                              void* d_out, int out_size, void* d_ws, size_t ws_size,
                              hipStream_t stream) {
    // inputs: 0 seq_len 1 freqs(16) 2 W1(256*128) 3 b1(256) 4 W2(32*256)
    //         5 b2(32) 6 dr(S*S) 7 dc(S*S)
    const float* freqs = (const float*)d_in[1];
    const float* W1    = (const float*)d_in[2];
    const float* b1    = (const float*)d_in[3];
    const float* W2    = (const float*)d_in[4];
    const float* b2    = (const float*)d_in[5];
    float4* out = (float4*)d_out;

    const int npairs = in_sizes[6];                // S*S = 1024*1024

    // ws layout: [table 508 KB][P 385 KB]
    const size_t TBL_B = (size_t)NPAIRS_TBL * TOUT * 4;
    float* table = (float*)d_ws;
    float* P     = (float*)((char*)d_ws + TBL_B);

    gab_ptab_kernel  <<<PROWS, 256, 0, stream>>>(freqs, W1, P);
    gab_table_kernel <<<(NPAIRS_TBL + 3) / 4, 256, 0, stream>>>(P, b1, W2, b2, table);
    gab_gather_kernel<<<2048, 256, 0, stream>>>(table, out, npairs);
}

// Round 17
// 39.803 us; speedup vs baseline: 1.8249x; 1.1731x over previous
//
#include <hip/hip_runtime.h>
#include <math.h>

// Problem constants (reference: POS_LEN=32, NUM_F=16, HIDDEN=256, T=32)
#define NUM_F   16
#define FIN     (8 * NUM_F)      // 128 fourier features
#define HIDDEN  256
#define TOUT    32
#define NOFF    63               // distinct offset values: -31..31
#define NSUM    125              // distinct dr+dc / dr-dc values: -62..62
#define NPAIRS_TBL (NOFF * NOFF) // 3969
#define PROWS   (NOFF + NOFF + NSUM + NSUM)      // 376 rows in P

// ---------------------------------------------------------------------------
// KP: layer-1 separable partials P[rho][h] (proven ~1.5 us; plain stores —
// R16 showed NT producer stores regress by forcing consumer reads to HBM).
__global__ __launch_bounds__(256) void gab_ptab_kernel(
    const float* __restrict__ freqs, const float* __restrict__ W1,
    float* __restrict__ P)
{
    __shared__ float fv[32];
    const int rho = blockIdx.x;
    int grp, val;
    if (rho < NOFF)                 { grp = 0; val = rho - 31; }
    else if (rho < 2 * NOFF)        { grp = 1; val = rho - NOFF - 31; }
    else if (rho < 2 * NOFF + NSUM) { grp = 2; val = rho - 2 * NOFF - 62; }
    else                            { grp = 3; val = rho - 2 * NOFF - NSUM - 62; }
    const int t = threadIdx.x;
    if (t < 32) {
        const float arg = (float)val * freqs[t & 15];
        fv[t] = (t < 16) ? sinf(arg) : cosf(arg);   // [sin16, cos16]
    }
    __syncthreads();
    const float4* __restrict__ w4 = (const float4*)(W1 + t * FIN + grp * 32);
    const float4* f4 = (const float4*)fv;           // same-addr broadcast
    float a0 = 0.f, a1 = 0.f, a2 = 0.f, a3 = 0.f;
    #pragma unroll
    for (int k = 0; k < 8; k += 2) {
        const float4 wa = w4[k], wb = w4[k + 1];
        const float4 fa = f4[k], fb = f4[k + 1];
        a0 = fmaf(wa.x, fa.x, a0); a1 = fmaf(wa.y, fa.y, a1);
        a2 = fmaf(wa.z, fa.z, a2); a3 = fmaf(wa.w, fa.w, a3);
        a0 = fmaf(wb.x, fb.x, a0); a1 = fmaf(wb.y, fb.y, a1);
        a2 = fmaf(wb.z, fb.z, a2); a3 = fmaf(wb.w, fb.w, a3);
    }
    P[rho * HIDDEN + t] = (a0 + a1) + (a2 + a3);
}

// ---------------------------------------------------------------------------
// KT v4: wave-per-pair, NO shuffle butterfly.
//  - W2 staged TRANSPOSED into LDS: w2t[k*33+o] (pad 33 -> bank (k+o)%32,
//    conflict-free scalar reads).
//  - wave writes its pair's h to a wave-local LDS slot (same-wave RAW, no
//    barrier); lane l computes output o=l&31 over half the k-range with
//    independent pipelined LDS reads + fma; ONE shfl_xor(32); coalesced
//    128-B store (no bitrev scatter).
__global__ __launch_bounds__(256) void gab_table_kernel(
    const float* __restrict__ P, const float* __restrict__ b1,
    const float* __restrict__ W2, const float* __restrict__ b2,
    float* __restrict__ table)
{
    __shared__ float  w2t[256 * 33];              // 33.8 KB transposed W2
    __shared__ float4 hbuf[4][64];                // 4 KB: per-wave h slots

    const int t    = threadIdx.x;
    const int w    = t >> 6;                      // wave 0..3
    const int l    = t & 63;
    const int pair = blockIdx.x * 4 + w;
    const bool valid = (pair < NPAIRS_TBL);
    const int cp   = valid ? pair : (NPAIRS_TBL - 1);   // clamp: safe loads

    // ---- issue P/b1 loads early (latency overlaps W2 staging) -----------
    const int ia = cp / NOFF;                     // dr + 31
    const int ib = cp % NOFF;                     // dc + 31
    const int ip = ia + ib;
    const int im = ia - ib + 62;
    const float4* __restrict__ P4 = (const float4*)P;
    const float4 pa = P4[(0 * NOFF          + ia) * 64 + l];
    const float4 pb = P4[(1 * NOFF          + ib) * 64 + l];
    const float4 pp = P4[(2 * NOFF          + ip) * 64 + l];
    const float4 pm = P4[((2 * NOFF + NSUM) + im) * 64 + l];
    const float4 bb = ((const float4*)b1)[l];

    // ---- stage W2 transposed: thread t writes w2t[t*33+q] = W2[q*256+t] ---
    // (coalesced global reads; LDS writes bank (t+q)%32: conflict-free)
    #pragma unroll 8
    for (int q = 0; q < 32; ++q)
        w2t[t * 33 + q] = W2[q * 256 + t];
    __syncthreads();

    // ---- hidden: h[4l..4l+3] -> wave-local LDS ---------------------------
    float h0 = pa.x + pb.x + pp.x + pm.x + bb.x;
    float h1 = pa.y + pb.y + pp.y + pm.y + bb.y;
    float h2 = pa.z + pb.z + pp.z + pm.z + bb.z;
    float h3 = pa.w + pb.w + pp.w + pm.w + bb.w;
    h0 = h0 / (1.0f + expf(-h0));
    h1 = h1 / (1.0f + expf(-h1));
    h2 = h2 / (1.0f + expf(-h2));
    h3 = h3 / (1.0f + expf(-h3));
    hbuf[w][l] = make_float4(h0, h1, h2, h3);     // same-wave RAW: lgkmcnt only

    // ---- layer 2: lane l -> output o over half the k range ----------------
    const int o     = l & 31;
    const int kb4   = (l >> 5) * 32;              // h quad base: 0 or 32
    const float* __restrict__ wcol = &w2t[(l >> 5) * 128 * 33 + o];
    float s = 0.f;
    #pragma unroll 8
    for (int k4 = 0; k4 < 32; ++k4) {
        const float4 h4 = hbuf[w][kb4 + k4];      // 2 bcast addrs: free
        const float* wr = wcol + k4 * 4 * 33;
        s = fmaf(h4.x, wr[0],      s);
        s = fmaf(h4.y, wr[33],     s);
        s = fmaf(h4.z, wr[66],     s);
        s = fmaf(h4.w, wr[99],     s);
    }
    s += __shfl_xor(s, 32);                       // merge the two k-halves

    if (valid && l < 32)
        table[pair * TOUT + o] = (s + b2[o]) * 0.17677669529663687f;
}

// ---------------------------------------------------------------------------
// Gather (plain stores — measured ~20.8 us write floor).
__global__ __launch_bounds__(256) void gab_gather_kernel(
    const float* __restrict__ table,
    float4* __restrict__ out, int npairs)
{
    const int total = npairs * 8;
    const int stride = gridDim.x * blockDim.x;
    const float4* __restrict__ tbl4 = (const float4*)table;
    for (int idx = blockIdx.x * blockDim.x + threadIdx.x; idx < total; idx += stride) {
        const int p = idx >> 3;
        const int l = idx & 7;
        const int i = p >> 10;
        const int j = p & 1023;
        const int ir = (i >> 5) - (j >> 5) + (NOFF / 2);
        const int ic = (i & 31) - (j & 31) + (NOFF / 2);
        out[idx] = tbl4[(ir * NOFF + ic) * (TOUT / 4) + l];
    }
}

// ---------------------------------------------------------------------------
extern "C" void kernel_launch(void* const* d_in, const int* in_sizes, int n_in,
                              void* d_out, int out_size, void* d_ws, size_t ws_size,
                              hipStream_t stream) {
    // inputs: 0 seq_len 1 freqs(16) 2 W1(256*128) 3 b1(256) 4 W2(32*256)
    //         5 b2(32) 6 dr(S*S) 7 dc(S*S)
    const float* freqs = (const float*)d_in[1];
    const float* W1    = (const float*)d_in[2];
    const float* b1    = (const float*)d_in[3];
    const float* W2    = (const float*)d_in[4];
    const float* b2    = (const float*)d_in[5];
    float4* out = (float4*)d_out;

    const int npairs = in_sizes[6];                // S*S = 1024*1024

    // ws layout: [table 508 KB][P 385 KB]
    const size_t TBL_B = (size_t)NPAIRS_TBL * TOUT * 4;
    float* table = (float*)d_ws;
    float* P     = (float*)((char*)d_ws + TBL_B);

    gab_ptab_kernel  <<<PROWS, 256, 0, stream>>>(freqs, W1, P);
    gab_table_kernel <<<(NPAIRS_TBL + 3) / 4, 256, 0, stream>>>(P, b1, W2, b2, table);
    gab_gather_kernel<<<2048, 256, 0, stream>>>(table, out, npairs);
}